// Round 1
// baseline (207.373 us; speedup 1.0000x reference)
//
#include <hip/hip_runtime.h>
#include <hip/hip_bf16.h>

#define B_ROWS 4096
#define N2 8192
#define DD 512

typedef __attribute__((ext_vector_type(8))) short short8v;
typedef __attribute__((ext_vector_type(4))) float float4v;

__device__ inline unsigned int f2bf(float f) {
  unsigned int u = __float_as_uint(f);
  u += 0x7fffu + ((u >> 16) & 1u);
  return u >> 16;
}
__device__ inline float bf2f(unsigned short b) {
  return __uint_as_float(((unsigned int)b) << 16);
}

// ---------------- normalize: z / max(||z||, 1e-8) -> bf16 ----------------
__global__ __launch_bounds__(256) void k_normalize(const float* __restrict__ f1,
                                                   const float* __restrict__ f2,
                                                   unsigned int* __restrict__ zn) {
  int row = blockIdx.x;
  const float* src = (row < B_ROWS) ? (f1 + (size_t)row * DD)
                                    : (f2 + (size_t)(row - B_ROWS) * DD);
  int t = threadIdx.x;
  float2 v = ((const float2*)src)[t];
  float ss = v.x * v.x + v.y * v.y;
#pragma unroll
  for (int off = 32; off; off >>= 1) ss += __shfl_down(ss, off, 64);
  __shared__ float wsum[4];
  if ((t & 63) == 0) wsum[t >> 6] = ss;
  __syncthreads();
  float tot = wsum[0] + wsum[1] + wsum[2] + wsum[3];
  float inv = 1.0f / fmaxf(sqrtf(tot), 1e-8f);
  unsigned int b0 = f2bf(v.x * inv);
  unsigned int b1 = f2bf(v.y * inv);
  zn[(size_t)row * (DD / 2) + t] = b0 | (b1 << 16);
}

// ---------------- targets: tpart[j] = (zn1_j.zn1_j + zn2_j.zn1_j) / T ----------------
__global__ __launch_bounds__(256) void k_targets(const unsigned short* __restrict__ zn,
                                                 float* __restrict__ tpart) {
  int j = blockIdx.x * 4 + (threadIdx.x >> 6);
  int lane = threadIdx.x & 63;
  short8v z1 = ((const short8v*)(zn + (size_t)j * DD))[lane];
  short8v z2 = ((const short8v*)(zn + (size_t)(B_ROWS + j) * DD))[lane];
  float d = 0.f;
#pragma unroll
  for (int e = 0; e < 8; ++e) {
    float a = bf2f((unsigned short)z1[e]);
    float b = bf2f((unsigned short)z2[e]);
    d += a * a + a * b;
  }
#pragma unroll
  for (int off = 32; off; off >>= 1) d += __shfl_down(d, off, 64);
  if (lane == 0) tpart[j] = d * 2.0f;  // 1/T = 2
}

// ---------------- main: S = zn.zn^T, rowsum[i] += sum_j exp(2*S - 2) ----------------
__global__ __launch_bounds__(256) void k_gemm_expsum(const unsigned short* __restrict__ zn,
                                                     float* __restrict__ rowsum) {
  __shared__ __align__(16) unsigned short As[128 * 64];
  __shared__ __align__(16) unsigned short Bs[128 * 64];
  int bj = blockIdx.x, bi = blockIdx.y;
  int tid = threadIdx.x;
  int lane = tid & 63, w = tid >> 6;
  int wr = w >> 1, wc = w & 1;

  float4v acc[4][4];
#pragma unroll
  for (int m = 0; m < 4; ++m)
#pragma unroll
    for (int n = 0; n < 4; ++n) acc[m][n] = {0.f, 0.f, 0.f, 0.f};

  const char* zb = (const char*)zn;
  const size_t rowbytes = DD * 2;  // 1024

  for (int k0 = 0; k0 < DD; k0 += 64) {
    // stage A-tile (rows bi*128..+127, k0..k0+63) and B-tile (rows bj*128..)
#pragma unroll
    for (int c = 0; c < 4; ++c) {
      int base = (w * 4 + c) << 10;   // wave-uniform LDS byte base (1KB per call)
      int lo = base + lane * 16;      // this lane's LDS byte dest (HW: base + lane*16)
      int r = lo >> 7;                // tile row (128B per row)
      int cb = lo & 127;              // byte within row
      const char* ga = zb + (size_t)(bi * 128 + r) * rowbytes + (size_t)k0 * 2 + cb;
      const char* gb = zb + (size_t)(bj * 128 + r) * rowbytes + (size_t)k0 * 2 + cb;
      __builtin_amdgcn_global_load_lds(
          (__attribute__((address_space(1))) void*)ga,
          (__attribute__((address_space(3))) void*)((char*)As + base), 16, 0, 0);
      __builtin_amdgcn_global_load_lds(
          (__attribute__((address_space(1))) void*)gb,
          (__attribute__((address_space(3))) void*)((char*)Bs + base), 16, 0, 0);
    }
    __syncthreads();
#pragma unroll
    for (int kk = 0; kk < 2; ++kk) {
      short8v a[4], b[4];
      int koff = kk * 64 + ((lane >> 4) << 4);  // byte offset of this lane's 8 k-elems
#pragma unroll
      for (int m = 0; m < 4; ++m) {
        int row = wr * 64 + m * 16 + (lane & 15);
        a[m] = *(const short8v*)((const char*)As + row * 128 + koff);
      }
#pragma unroll
      for (int n = 0; n < 4; ++n) {
        int row = wc * 64 + n * 16 + (lane & 15);
        b[n] = *(const short8v*)((const char*)Bs + row * 128 + koff);
      }
#pragma unroll
      for (int m = 0; m < 4; ++m)
#pragma unroll
        for (int n = 0; n < 4; ++n)
          acc[m][n] = __builtin_amdgcn_mfma_f32_16x16x32_bf16(a[m], b[n], acc[m][n], 0, 0, 0);
    }
    __syncthreads();
  }

  // epilogue: e = exp(logit - 2) = exp2(C*(dot-1)), C = 2*log2(e)
  const float C = 2.88539008177792681f;
  float ev[4][4];
#pragma unroll
  for (int m = 0; m < 4; ++m)
#pragma unroll
    for (int r = 0; r < 4; ++r) ev[m][r] = 0.f;
#pragma unroll
  for (int m = 0; m < 4; ++m)
#pragma unroll
    for (int n = 0; n < 4; ++n)
#pragma unroll
      for (int r = 0; r < 4; ++r)
        ev[m][r] += exp2f(fmaf(acc[m][n][r], C, -C));

  // 16-lane (column-group) reduce, then one atomic per row per wave
#pragma unroll
  for (int m = 0; m < 4; ++m)
#pragma unroll
    for (int r = 0; r < 4; ++r) {
      float v = ev[m][r];
      v += __shfl_xor(v, 1);
      v += __shfl_xor(v, 2);
      v += __shfl_xor(v, 4);
      v += __shfl_xor(v, 8);
      if ((lane & 15) == 0) {
        int grow = bi * 128 + wr * 64 + m * 16 + ((lane >> 4) << 2) + r;
        atomicAdd(&rowsum[grow], v);
      }
    }
}

// ---------------- finalize: loss = (sum(2 + log rowsum) - sum tpart) / 8192 ----------------
__global__ __launch_bounds__(256) void k_finalize(const float* __restrict__ rowsum,
                                                  const float* __restrict__ tpart,
                                                  float* __restrict__ out) {
  int t = threadIdx.x;
  float acc = 0.f;
  for (int i = t; i < N2; i += 256) acc += 2.0f + logf(rowsum[i]);
  for (int i = t; i < B_ROWS; i += 256) acc -= tpart[i];
#pragma unroll
  for (int off = 32; off; off >>= 1) acc += __shfl_down(acc, off, 64);
  __shared__ float wsum[4];
  if ((t & 63) == 0) wsum[t >> 6] = acc;
  __syncthreads();
  if (t == 0) out[0] = (wsum[0] + wsum[1] + wsum[2] + wsum[3]) * (1.0f / (float)N2);
}

extern "C" void kernel_launch(void* const* d_in, const int* in_sizes, int n_in,
                              void* d_out, int out_size, void* d_ws, size_t ws_size,
                              hipStream_t stream) {
  const float* f1 = (const float*)d_in[0];
  const float* f2 = (const float*)d_in[1];
  float* out = (float*)d_out;
  char* ws = (char*)d_ws;

  unsigned int* zn_w = (unsigned int*)ws;                      // 8192*512*2 = 8 MB (bf16)
  unsigned short* zn = (unsigned short*)ws;
  float* rowsum = (float*)(ws + (size_t)N2 * DD * 2);          // 32 KB
  float* tpart = rowsum + N2;                                  // 16 KB

  hipMemsetAsync(rowsum, 0, N2 * sizeof(float), stream);
  k_normalize<<<N2, 256, 0, stream>>>(f1, f2, zn_w);
  k_targets<<<B_ROWS / 4, 256, 0, stream>>>(zn, tpart);
  k_gemm_expsum<<<dim3(64, 64), 256, 0, stream>>>(zn, rowsum);
  k_finalize<<<1, 256, 0, stream>>>(rowsum, tpart, out);
}

// Round 2
// 117.930 us; speedup vs baseline: 1.7584x; 1.7584x over previous
//
#include <hip/hip_runtime.h>
#include <hip/hip_bf16.h>

#define B_ROWS 4096
#define N2 8192
#define DD 512
#define NB 64  // 8192 / 128 tile-blocks per dim

typedef __attribute__((ext_vector_type(8))) short short8v;
typedef __attribute__((ext_vector_type(4))) float float4v;

__device__ inline unsigned int f2bf(float f) {
  unsigned int u = __float_as_uint(f);
  u += 0x7fffu + ((u >> 16) & 1u);
  return u >> 16;
}
__device__ inline float bf2f(unsigned short b) {
  return __uint_as_float(((unsigned int)b) << 16);
}

// ---------------- normalize: z / max(||z||,1e-8) -> bf16, one wave per row ----------------
__global__ __launch_bounds__(256) void k_normalize(const float* __restrict__ f1,
                                                   const float* __restrict__ f2,
                                                   uint4* __restrict__ zn) {
  int row = blockIdx.x * 4 + (threadIdx.x >> 6);
  int lane = threadIdx.x & 63;
  const float* src = (row < B_ROWS) ? (f1 + (size_t)row * DD)
                                    : (f2 + (size_t)(row - B_ROWS) * DD);
  const float4* s4 = (const float4*)src;
  float4 v0 = s4[lane * 2];
  float4 v1 = s4[lane * 2 + 1];
  float ss = v0.x * v0.x + v0.y * v0.y + v0.z * v0.z + v0.w * v0.w +
             v1.x * v1.x + v1.y * v1.y + v1.z * v1.z + v1.w * v1.w;
#pragma unroll
  for (int off = 1; off < 64; off <<= 1) ss += __shfl_xor(ss, off, 64);
  float inv = 1.0f / fmaxf(sqrtf(ss), 1e-8f);
  uint4 p;
  p.x = f2bf(v0.x * inv) | (f2bf(v0.y * inv) << 16);
  p.y = f2bf(v0.z * inv) | (f2bf(v0.w * inv) << 16);
  p.z = f2bf(v1.x * inv) | (f2bf(v1.y * inv) << 16);
  p.w = f2bf(v1.z * inv) | (f2bf(v1.w * inv) << 16);
  zn[(size_t)row * (DD / 8) + lane] = p;
}

// ---------------- targets: tpart[j] = 2*(zn1_j.zn1_j + zn2_j.zn1_j) ----------------
__global__ __launch_bounds__(256) void k_targets(const unsigned short* __restrict__ zn,
                                                 float* __restrict__ tpart) {
  int j = blockIdx.x * 4 + (threadIdx.x >> 6);
  int lane = threadIdx.x & 63;
  short8v z1 = ((const short8v*)(zn + (size_t)j * DD))[lane];
  short8v z2 = ((const short8v*)(zn + (size_t)(B_ROWS + j) * DD))[lane];
  float d = 0.f;
#pragma unroll
  for (int e = 0; e < 8; ++e) {
    float a = bf2f((unsigned short)z1[e]);
    float b = bf2f((unsigned short)z2[e]);
    d += a * a + a * b;
  }
#pragma unroll
  for (int off = 32; off; off >>= 1) d += __shfl_down(d, off, 64);
  if (lane == 0) tpart[j] = d * 2.0f;  // 1/T = 2
}

// ---------------- main: upper-triangular tiles of S = zn.zn^T ----------------
// rowsum[i] += sum_j exp(2*S_ij - 2); off-diagonal tiles also add their
// column-sums to rowsum[j] (exp(S) is symmetric).
__global__ __launch_bounds__(256) void k_gemm_expsum(const unsigned short* __restrict__ zn,
                                                     float* __restrict__ rowsum) {
  __shared__ __align__(16) unsigned short As[128 * 64];
  __shared__ __align__(16) unsigned short Bs[128 * 64];

  // triangular decode: t -> (bi, bj) with bi <= bj
  int t = blockIdx.x;
  int bi = (int)((129.0 - sqrt(16641.0 - 8.0 * (double)t)) * 0.5);
  // offset(b) = b*64 - b*(b-1)/2
  while ((bi + 1) * NB - ((bi + 1) * bi) / 2 <= t) ++bi;
  while (bi * NB - (bi * (bi - 1)) / 2 > t) --bi;
  int bj = bi + (t - (bi * NB - (bi * (bi - 1)) / 2));

  int tid = threadIdx.x;
  int lane = tid & 63, w = tid >> 6;
  int wr = w >> 1, wc = w & 1;

  float4v acc[4][4];
#pragma unroll
  for (int m = 0; m < 4; ++m)
#pragma unroll
    for (int n = 0; n < 4; ++n) acc[m][n] = {0.f, 0.f, 0.f, 0.f};

  const char* zb = (const char*)zn;
  const size_t rowbytes = DD * 2;  // 1024

  for (int k0 = 0; k0 < DD; k0 += 64) {
#pragma unroll
    for (int c = 0; c < 4; ++c) {
      int base = (w * 4 + c) << 10;   // wave-uniform LDS byte base
      int lo = base + lane * 16;      // linear LDS dest (HW: base + lane*16)
      int r = lo >> 7;                // tile row (128B per row)
      int cb = (lo & 127) ^ ((r & 7) << 4);  // pre-swizzled SOURCE column (rule #21)
      const char* ga = zb + (size_t)(bi * 128 + r) * rowbytes + (size_t)k0 * 2 + cb;
      const char* gb = zb + (size_t)(bj * 128 + r) * rowbytes + (size_t)k0 * 2 + cb;
      __builtin_amdgcn_global_load_lds(
          (__attribute__((address_space(1))) void*)ga,
          (__attribute__((address_space(3))) void*)((char*)As + base), 16, 0, 0);
      __builtin_amdgcn_global_load_lds(
          (__attribute__((address_space(1))) void*)gb,
          (__attribute__((address_space(3))) void*)((char*)Bs + base), 16, 0, 0);
    }
    __syncthreads();
#pragma unroll
    for (int kk = 0; kk < 2; ++kk) {
      short8v a[4], b[4];
      int koff = kk * 64 + ((lane >> 4) << 4);
#pragma unroll
      for (int m = 0; m < 4; ++m) {
        int row = wr * 64 + m * 16 + (lane & 15);
        a[m] = *(const short8v*)((const char*)As + row * 128 + (koff ^ ((row & 7) << 4)));
      }
#pragma unroll
      for (int n = 0; n < 4; ++n) {
        int row = wc * 64 + n * 16 + (lane & 15);
        b[n] = *(const short8v*)((const char*)Bs + row * 128 + (koff ^ ((row & 7) << 4)));
      }
#pragma unroll
      for (int m = 0; m < 4; ++m)
#pragma unroll
        for (int n = 0; n < 4; ++n)
          acc[m][n] = __builtin_amdgcn_mfma_f32_16x16x32_bf16(a[m], b[n], acc[m][n], 0, 0, 0);
    }
    __syncthreads();
  }

  // epilogue: e = exp(2*dot - 2) = exp2(C*dot - C), C = 2*log2(e)
  const float C = 2.88539008177792681f;
  float rowacc[4][4];
  float colacc[4];
#pragma unroll
  for (int m = 0; m < 4; ++m)
#pragma unroll
    for (int r = 0; r < 4; ++r) rowacc[m][r] = 0.f;
#pragma unroll
  for (int n = 0; n < 4; ++n) colacc[n] = 0.f;

#pragma unroll
  for (int m = 0; m < 4; ++m)
#pragma unroll
    for (int n = 0; n < 4; ++n) {
      float s = 0.f;
#pragma unroll
      for (int r = 0; r < 4; ++r) {
        float e = exp2f(fmaf(acc[m][n][r], C, -C));
        rowacc[m][r] += e;
        s += e;
      }
      colacc[n] += s;
    }

  // row-sums: reduce over columns (lane&15), one atomic per row per wave
#pragma unroll
  for (int m = 0; m < 4; ++m)
#pragma unroll
    for (int r = 0; r < 4; ++r) {
      float v = rowacc[m][r];
      v += __shfl_xor(v, 1);
      v += __shfl_xor(v, 2);
      v += __shfl_xor(v, 4);
      v += __shfl_xor(v, 8);
      if ((lane & 15) == 0) {
        int grow = bi * 128 + wr * 64 + m * 16 + ((lane >> 4) << 2) + r;
        atomicAdd(&rowsum[grow], v);
      }
    }

  // col-sums (symmetric contribution), only off-diagonal tiles
  if (bi != bj) {
#pragma unroll
    for (int n = 0; n < 4; ++n) {
      float v = colacc[n];
      v += __shfl_xor(v, 16);
      v += __shfl_xor(v, 32);
      if (lane < 16) {
        int gcol = bj * 128 + wc * 64 + n * 16 + lane;
        atomicAdd(&rowsum[gcol], v);
      }
    }
  }
}

// ---------------- finalize: loss = (sum(2 + log rowsum) - sum tpart) / 8192 ----------------
__global__ __launch_bounds__(256) void k_finalize(const float* __restrict__ rowsum,
                                                  const float* __restrict__ tpart,
                                                  float* __restrict__ out) {
  int t = threadIdx.x;
  float acc = 0.f;
  for (int i = t; i < N2; i += 256) acc += 2.0f + logf(rowsum[i]);
  for (int i = t; i < B_ROWS; i += 256) acc -= tpart[i];
#pragma unroll
  for (int off = 32; off; off >>= 1) acc += __shfl_down(acc, off, 64);
  __shared__ float wsum[4];
  if ((t & 63) == 0) wsum[t >> 6] = acc;
  __syncthreads();
  if (t == 0) out[0] = (wsum[0] + wsum[1] + wsum[2] + wsum[3]) * (1.0f / (float)N2);
}

extern "C" void kernel_launch(void* const* d_in, const int* in_sizes, int n_in,
                              void* d_out, int out_size, void* d_ws, size_t ws_size,
                              hipStream_t stream) {
  const float* f1 = (const float*)d_in[0];
  const float* f2 = (const float*)d_in[1];
  float* out = (float*)d_out;
  char* ws = (char*)d_ws;

  uint4* zn_w = (uint4*)ws;                                    // 8192*512*2 = 8 MB (bf16)
  unsigned short* zn = (unsigned short*)ws;
  float* rowsum = (float*)(ws + (size_t)N2 * DD * 2);          // 32 KB
  float* tpart = rowsum + N2;                                  // 16 KB

  hipMemsetAsync(rowsum, 0, N2 * sizeof(float), stream);
  k_normalize<<<N2 / 4, 256, 0, stream>>>(f1, f2, zn_w);
  k_targets<<<B_ROWS / 4, 256, 0, stream>>>(zn, tpart);
  k_gemm_expsum<<<(NB * (NB + 1)) / 2, 256, 0, stream>>>(zn, rowsum);
  k_finalize<<<1, 256, 0, stream>>>(rowsum, tpart, out);
}